// Round 4
// baseline (1578.300 us; speedup 1.0000x reference)
//
#include <hip/hip_runtime.h>

#define N_NODES 100000
#define N_EDGES 1600000
#define DIM 128
#define BSHIFT 6
#define NPB 64                      // nodes per bucket
#define NB 1563                     // ceil(100000/64)

// ---------------- workspace layout (bytes, 128-aligned) --------------------
#define OFF_H       0               // bf16 [N_NODES][128]   25,600,000
#define OFF_BBASE   25600000        // int [NB+1]                 6,400
#define OFF_BCURS   25606400        // int [NB]                   6,400
#define OFF_BCNT    25612800        // int [NB]                   6,400
#define OFF_EPACK   25619200        // uint2 [N_EDGES]       12,800,000
#define WS_NEED     38419200

static __device__ __forceinline__ unsigned short f2bf(float f) {
    union { float f; unsigned u; } a; a.f = f;
    unsigned r = a.u + 0x7fffu + ((a.u >> 16) & 1u);  // round-to-nearest-even
    return (unsigned short)(r >> 16);
}

// ---------------------------------------------------------------------------
// zero helpers
// ---------------------------------------------------------------------------
__global__ __launch_bounds__(256) void zero_out_kernel(float4* __restrict__ out) {
    int i = blockIdx.x * 256 + threadIdx.x;
    if (i < N_NODES * DIM / 4) out[i] = make_float4(0.f, 0.f, 0.f, 0.f);
}

__global__ __launch_bounds__(256) void zero_cnt_kernel(int* __restrict__ bcnt) {
    int i = blockIdx.x * 256 + threadIdx.x;
    if (i < NB) bcnt[i] = 0;
}

// ---------------------------------------------------------------------------
// GEMM h = x @ W^T (fp32 accumulate, bf16 output). Unchanged from R3.
// ---------------------------------------------------------------------------
#define GR 64
__global__ __launch_bounds__(256) void gemm_tiled_kernel(
        const float4* __restrict__ x4,        // [N_NODES][32]
        const float4* __restrict__ W4,        // [128][32]
        unsigned int* __restrict__ hbits)     // [N_NODES][64] (2 bf16 / uint)
{
    __shared__ float xs[GR][68];
    __shared__ float wsh[64][132];

    const int t  = threadIdx.x;
    const int tx = t & 15;
    const int ty = t >> 4;
    const int r0 = blockIdx.x * GR;

    float acc[4][8];
#pragma unroll
    for (int i = 0; i < 4; ++i)
#pragma unroll
        for (int j = 0; j < 8; ++j) acc[i][j] = 0.f;

    for (int kc = 0; kc < 2; ++kc) {
#pragma unroll
        for (int i = 0; i < 4; ++i) {
            int linear = t + 256 * i;
            int r  = linear >> 4;
            int k4 = linear & 15;
            float4 v = make_float4(0.f, 0.f, 0.f, 0.f);
            if (r0 + r < N_NODES) v = x4[(size_t)(r0 + r) * 32 + kc * 16 + k4];
            *(float4*)&xs[r][k4 * 4] = v;
        }
#pragma unroll
        for (int i = 0; i < 8; ++i) {
            int linear = t + 256 * i;
            int c  = linear >> 4;
            int k4 = linear & 15;
            float4 v = W4[(size_t)c * 32 + kc * 16 + k4];
            wsh[k4 * 4 + 0][c] = v.x;
            wsh[k4 * 4 + 1][c] = v.y;
            wsh[k4 * 4 + 2][c] = v.z;
            wsh[k4 * 4 + 3][c] = v.w;
        }
        __syncthreads();

#pragma unroll 4
        for (int kk = 0; kk < 64; ++kk) {
            float xf[4], wf[8];
#pragma unroll
            for (int i = 0; i < 4; ++i) xf[i] = xs[ty * 4 + i][kk];
            float4 wlo = *(const float4*)&wsh[kk][tx * 8];
            float4 whi = *(const float4*)&wsh[kk][tx * 8 + 4];
            wf[0] = wlo.x; wf[1] = wlo.y; wf[2] = wlo.z; wf[3] = wlo.w;
            wf[4] = whi.x; wf[5] = whi.y; wf[6] = whi.z; wf[7] = whi.w;
#pragma unroll
            for (int i = 0; i < 4; ++i)
#pragma unroll
                for (int j = 0; j < 8; ++j) acc[i][j] += xf[i] * wf[j];
        }
        __syncthreads();
    }

#pragma unroll
    for (int i = 0; i < 4; ++i) {
        int r = r0 + ty * 4 + i;
        if (r < N_NODES) {
            uint4 u;
            u.x = (unsigned)f2bf(acc[i][0]) | ((unsigned)f2bf(acc[i][1]) << 16);
            u.y = (unsigned)f2bf(acc[i][2]) | ((unsigned)f2bf(acc[i][3]) << 16);
            u.z = (unsigned)f2bf(acc[i][4]) | ((unsigned)f2bf(acc[i][5]) << 16);
            u.w = (unsigned)f2bf(acc[i][6]) | ((unsigned)f2bf(acc[i][7]) << 16);
            *(uint4*)&hbits[(size_t)r * 64 + tx * 4] = u;
        }
    }
}

// ---------------------------------------------------------------------------
// Coarse histogram over NB buckets (LDS-local, then merge)
// ---------------------------------------------------------------------------
__global__ __launch_bounds__(256) void hist_kernel(const int* __restrict__ dst,
                                                   int* __restrict__ bcnt) {
    __shared__ int lh[NB];
    for (int i = threadIdx.x; i < NB; i += 256) lh[i] = 0;
    __syncthreads();
    const int stride = gridDim.x * 256;
    for (int e = blockIdx.x * 256 + threadIdx.x; e < N_EDGES; e += stride)
        atomicAdd(&lh[dst[e] >> BSHIFT], 1);
    __syncthreads();
    for (int i = threadIdx.x; i < NB; i += 256) {
        int c = lh[i];
        if (c) atomicAdd(&bcnt[i], c);
    }
}

// ---------------------------------------------------------------------------
// Single-block scan of NB bucket counts -> bbase (exclusive), bcurs copy
// ---------------------------------------------------------------------------
__global__ __launch_bounds__(1024) void scan_kernel(const int* __restrict__ bcnt,
                                                    int* __restrict__ bbase,
                                                    int* __restrict__ bcurs) {
    __shared__ int wsum[16];
    const int t = threadIdx.x, lane = t & 63, wv = t >> 6;
    const int i0 = 2 * t, i1 = 2 * t + 1;
    int c0 = (i0 < NB) ? bcnt[i0] : 0;
    int c1 = (i1 < NB) ? bcnt[i1] : 0;
    int s = c0 + c1;

    int v = s;
#pragma unroll
    for (int off = 1; off < 64; off <<= 1) {
        int u = __shfl_up(v, off, 64);
        if (lane >= off) v += u;
    }
    if (lane == 63) wsum[wv] = v;
    __syncthreads();
    if (wv == 0 && lane < 16) {
        int ws = wsum[lane];
#pragma unroll
        for (int off = 1; off < 16; off <<= 1) {
            int u = __shfl_up(ws, off, 64);
            if (lane >= off) ws += u;
        }
        wsum[lane] = ws;
    }
    __syncthreads();

    int wexcl = wv ? wsum[wv - 1] : 0;
    int p = wexcl + (v - s);
    if (i0 < NB) { bbase[i0] = p;      bcurs[i0] = p; }
    if (i1 < NB) { bbase[i1] = p + c0; bcurs[i1] = p + c0; }
    if (t == 0) bbase[NB] = N_EDGES;
}

// ---------------------------------------------------------------------------
// Bucket fill: write frontier = NB cache lines (L2-resident), no amplification.
// Pack: bits 0..16 src, bits 17..22 dst&63; .y = val bits.
// ---------------------------------------------------------------------------
__global__ __launch_bounds__(256) void fill_kernel(const int* __restrict__ src,
                                                   const int* __restrict__ dst,
                                                   const float* __restrict__ vals,
                                                   int* __restrict__ bcurs,
                                                   uint2* __restrict__ ep) {
    int e = blockIdx.x * 256 + threadIdx.x;
    if (e < N_EDGES) {
        int d = dst[e];
        int pos = atomicAdd(&bcurs[d >> BSHIFT], 1);
        ep[pos] = make_uint2((unsigned)src[e] | ((unsigned)(d & 63) << 17),
                             __float_as_uint(vals[e]));
    }
}

// ---------------------------------------------------------------------------
// Bucket gather: one block per bucket, 32 KB LDS fp32 accumulator (5 blk/CU).
// acc[node][pair][lane]: bank = lane%32 -> 2-way alias (free). ds_add_f32.
// Each out row written exactly once.
// ---------------------------------------------------------------------------
__global__ __launch_bounds__(256) void gather_kernel(
        const unsigned int* __restrict__ hbits,  // [N_NODES][64]
        const int* __restrict__ bbase,
        const uint2* __restrict__ ep,
        float2* __restrict__ out2)
{
    __shared__ float acc[NPB][2][64];   // 32 KB

    const int t = threadIdx.x, lane = t & 63, wv = t >> 6;
    const int b = blockIdx.x;

    float4* az = (float4*)&acc[0][0][0];
    for (int i = t; i < NPB * 2 * 64 / 4; i += 256)
        az[i] = make_float4(0.f, 0.f, 0.f, 0.f);
    __syncthreads();

    const int jb = bbase[b], je = bbase[b + 1];
    int j = jb + wv;
    for (; j + 4 < je; j += 8) {            // 2 edges in flight per wave
        uint2 e0 = ep[j], e1 = ep[j + 4];
        unsigned s0 = e0.x & 0x1FFFFu, s1 = e1.x & 0x1FFFFu;
        unsigned hb0 = hbits[(size_t)s0 * 64 + lane];
        unsigned hb1 = hbits[(size_t)s1 * 64 + lane];
        float v0 = __uint_as_float(e0.y), v1 = __uint_as_float(e1.y);
        int d0 = (e0.x >> 17) & 63, d1 = (e1.x >> 17) & 63;
        atomicAdd(&acc[d0][0][lane], v0 * __uint_as_float(hb0 << 16));
        atomicAdd(&acc[d0][1][lane], v0 * __uint_as_float(hb0 & 0xffff0000u));
        atomicAdd(&acc[d1][0][lane], v1 * __uint_as_float(hb1 << 16));
        atomicAdd(&acc[d1][1][lane], v1 * __uint_as_float(hb1 & 0xffff0000u));
    }
    for (; j < je; j += 4) {
        uint2 e0 = ep[j];
        unsigned s0 = e0.x & 0x1FFFFu;
        unsigned hb0 = hbits[(size_t)s0 * 64 + lane];
        float v0 = __uint_as_float(e0.y);
        int d0 = (e0.x >> 17) & 63;
        atomicAdd(&acc[d0][0][lane], v0 * __uint_as_float(hb0 << 16));
        atomicAdd(&acc[d0][1][lane], v0 * __uint_as_float(hb0 & 0xffff0000u));
    }
    __syncthreads();

    // writeout: wave wv -> nodes wv*16 .. wv*16+15 (coalesced 512 B stores)
#pragma unroll
    for (int i = 0; i < 16; ++i) {
        int n = wv * 16 + i;
        int node = b * NPB + n;
        if (node < N_NODES)
            out2[(size_t)node * 64 + lane] =
                make_float2(acc[n][0][lane], acc[n][1][lane]);
    }
}

// ---------------------------------------------------------------------------
// Fallback scatter (atomic) on bf16 h, if workspace too small
// ---------------------------------------------------------------------------
__global__ __launch_bounds__(256) void scatter_kernel(
        const unsigned int* __restrict__ hbits, const float* __restrict__ vals,
        const int* __restrict__ src, const int* __restrict__ dst,
        float* __restrict__ out)
{
    const int lane = threadIdx.x & 63;
    int e = (blockIdx.x * 256 + threadIdx.x) >> 6;
    if (e >= N_EDGES) return;
    const int   s = src[e];
    const int   d = dst[e];
    const float v = vals[e];
    unsigned b = hbits[(size_t)s * 64 + lane];
    float* op = out + (size_t)d * DIM + lane * 2;
    atomicAdd(op + 0, v * __uint_as_float(b << 16));
    atomicAdd(op + 1, v * __uint_as_float(b & 0xffff0000u));
}

// ---------------------------------------------------------------------------
extern "C" void kernel_launch(void* const* d_in, const int* in_sizes, int n_in,
                              void* d_out, int out_size, void* d_ws, size_t ws_size,
                              hipStream_t stream) {
    const float* x    = (const float*)d_in[0];
    const float* W    = (const float*)d_in[1];
    const float* vals = (const float*)d_in[2];
    const int*   src  = (const int*)d_in[3];
    const int*   dst  = (const int*)d_in[4];
    float* out = (float*)d_out;

    char* ws = (char*)d_ws;
    unsigned* hbits = (unsigned*)(ws + OFF_H);
    int*   bbase    = (int*)  (ws + OFF_BBASE);
    int*   bcurs    = (int*)  (ws + OFF_BCURS);
    int*   bcnt     = (int*)  (ws + OFF_BCNT);
    uint2* ep       = (uint2*)(ws + OFF_EPACK);

    // GEMM: h = bf16(x @ W^T)
    gemm_tiled_kernel<<<(N_NODES + GR - 1) / GR, 256, 0, stream>>>(
        (const float4*)x, (const float4*)W, hbits);

    if (ws_size >= (size_t)WS_NEED) {
        zero_cnt_kernel<<<(NB + 255) / 256, 256, 0, stream>>>(bcnt);
        hist_kernel<<<256, 256, 0, stream>>>(dst, bcnt);
        scan_kernel<<<1, 1024, 0, stream>>>(bcnt, bbase, bcurs);
        fill_kernel<<<(N_EDGES + 255) / 256, 256, 0, stream>>>(src, dst, vals,
                                                               bcurs, ep);
        gather_kernel<<<NB, 256, 0, stream>>>(hbits, bbase, ep, (float2*)out);
    } else {
        zero_out_kernel<<<(N_NODES * DIM / 4 + 255) / 256, 256, 0, stream>>>((float4*)out);
        scatter_kernel<<<(N_EDGES * 64 + 255) / 256, 256, 0, stream>>>(
            hbits, vals, src, dst, out);
    }
}

// Round 5
// 577.992 us; speedup vs baseline: 2.7307x; 2.7307x over previous
//
#include <hip/hip_runtime.h>

#define N_NODES 100000
#define N_EDGES 1600000
#define DIM 128
#define BSHIFT 6
#define NPB 64                      // nodes per bucket
#define NB 1563                     // ceil(100000/64)
#define NBLK_SCAN 98                // ceil(100000/1024)

// ---------------- workspace layout (bytes, 128-aligned) --------------------
#define OFF_H       0               // bf16 [N_NODES][128]   25,600,000
#define OFF_ROWPTR  25600000        // int [N_NODES+1]          400,128
#define OFF_COUNTS  26000128        // int [N_NODES pad]        400,128
#define OFF_BSUM    26400256        // int[128] bsum + int[128] boffset  1,024
#define OFF_BCURS   26401280        // int [NB]                   6,400
#define OFF_ETMP    26407680        // uint2 [N_EDGES]       12,800,000
#define OFF_EPACK   39207680        // uint2 [N_EDGES]       12,800,000
#define WS_NEED     52007680

static __device__ __forceinline__ unsigned short f2bf(float f) {
    union { float f; unsigned u; } a; a.f = f;
    unsigned r = a.u + 0x7fffu + ((a.u >> 16) & 1u);  // round-to-nearest-even
    return (unsigned short)(r >> 16);
}

// ---------------------------------------------------------------------------
// zero helpers
// ---------------------------------------------------------------------------
__global__ __launch_bounds__(256) void zero_out_kernel(float4* __restrict__ out) {
    int i = blockIdx.x * 256 + threadIdx.x;
    if (i < N_NODES * DIM / 4) out[i] = make_float4(0.f, 0.f, 0.f, 0.f);
}

__global__ __launch_bounds__(256) void zero_counts_kernel(int4* __restrict__ c4) {
    int i = blockIdx.x * 256 + threadIdx.x;
    if (i < 100032 / 4) c4[i] = make_int4(0, 0, 0, 0);
}

// ---------------------------------------------------------------------------
// GEMM h = x @ W^T (fp32 accumulate, bf16 output). Unchanged from R3.
// ---------------------------------------------------------------------------
#define GR 64
__global__ __launch_bounds__(256) void gemm_tiled_kernel(
        const float4* __restrict__ x4,        // [N_NODES][32]
        const float4* __restrict__ W4,        // [128][32]
        unsigned int* __restrict__ hbits)     // [N_NODES][64] (2 bf16 / uint)
{
    __shared__ float xs[GR][68];
    __shared__ float wsh[64][132];

    const int t  = threadIdx.x;
    const int tx = t & 15;
    const int ty = t >> 4;
    const int r0 = blockIdx.x * GR;

    float acc[4][8];
#pragma unroll
    for (int i = 0; i < 4; ++i)
#pragma unroll
        for (int j = 0; j < 8; ++j) acc[i][j] = 0.f;

    for (int kc = 0; kc < 2; ++kc) {
#pragma unroll
        for (int i = 0; i < 4; ++i) {
            int linear = t + 256 * i;
            int r  = linear >> 4;
            int k4 = linear & 15;
            float4 v = make_float4(0.f, 0.f, 0.f, 0.f);
            if (r0 + r < N_NODES) v = x4[(size_t)(r0 + r) * 32 + kc * 16 + k4];
            *(float4*)&xs[r][k4 * 4] = v;
        }
#pragma unroll
        for (int i = 0; i < 8; ++i) {
            int linear = t + 256 * i;
            int c  = linear >> 4;
            int k4 = linear & 15;
            float4 v = W4[(size_t)c * 32 + kc * 16 + k4];
            wsh[k4 * 4 + 0][c] = v.x;
            wsh[k4 * 4 + 1][c] = v.y;
            wsh[k4 * 4 + 2][c] = v.z;
            wsh[k4 * 4 + 3][c] = v.w;
        }
        __syncthreads();

#pragma unroll 4
        for (int kk = 0; kk < 64; ++kk) {
            float xf[4], wf[8];
#pragma unroll
            for (int i = 0; i < 4; ++i) xf[i] = xs[ty * 4 + i][kk];
            float4 wlo = *(const float4*)&wsh[kk][tx * 8];
            float4 whi = *(const float4*)&wsh[kk][tx * 8 + 4];
            wf[0] = wlo.x; wf[1] = wlo.y; wf[2] = wlo.z; wf[3] = wlo.w;
            wf[4] = whi.x; wf[5] = whi.y; wf[6] = whi.z; wf[7] = whi.w;
#pragma unroll
            for (int i = 0; i < 4; ++i)
#pragma unroll
                for (int j = 0; j < 8; ++j) acc[i][j] += xf[i] * wf[j];
        }
        __syncthreads();
    }

#pragma unroll
    for (int i = 0; i < 4; ++i) {
        int r = r0 + ty * 4 + i;
        if (r < N_NODES) {
            uint4 u;
            u.x = (unsigned)f2bf(acc[i][0]) | ((unsigned)f2bf(acc[i][1]) << 16);
            u.y = (unsigned)f2bf(acc[i][2]) | ((unsigned)f2bf(acc[i][3]) << 16);
            u.z = (unsigned)f2bf(acc[i][4]) | ((unsigned)f2bf(acc[i][5]) << 16);
            u.w = (unsigned)f2bf(acc[i][6]) | ((unsigned)f2bf(acc[i][7]) << 16);
            *(uint4*)&hbits[(size_t)r * 64 + tx * 4] = u;
        }
    }
}

// ---------------------------------------------------------------------------
// Per-node histogram
// ---------------------------------------------------------------------------
__global__ __launch_bounds__(256) void hist_kernel(const int* __restrict__ dst,
                                                   int* __restrict__ counts) {
    int e = blockIdx.x * 256 + threadIdx.x;
    if (e < N_EDGES) atomicAdd(&counts[dst[e]], 1);
}

// ---------------------------------------------------------------------------
// Multi-block scan (3 kernels) -> row_ptr; scan_write also seeds bcurs
// ---------------------------------------------------------------------------
__global__ __launch_bounds__(256) void scan_bsum_kernel(const int* __restrict__ counts,
                                                        int* __restrict__ bsum) {
    __shared__ int wsh[4];
    const int t = threadIdx.x, lane = t & 63, wv = t >> 6;
    int idx = blockIdx.x * 1024 + t * 4;
    int s = 0;
    if (idx < N_NODES) {   // N_NODES % 4 == 0 -> whole int4 in-bounds
        int4 c = *(const int4*)(counts + idx);
        s = c.x + c.y + c.z + c.w;
    }
#pragma unroll
    for (int off = 32; off > 0; off >>= 1) s += __shfl_down(s, off, 64);
    if (lane == 0) wsh[wv] = s;
    __syncthreads();
    if (t == 0) bsum[blockIdx.x] = wsh[0] + wsh[1] + wsh[2] + wsh[3];
}

__global__ __launch_bounds__(64) void scan_boff_kernel(const int* __restrict__ bsum,
                                                       int* __restrict__ boffset,
                                                       int* __restrict__ row_ptr) {
    const int t = threadIdx.x;  // 0..63, each owns elements 2t, 2t+1
    int c0 = (2 * t     < NBLK_SCAN) ? bsum[2 * t]     : 0;
    int c1 = (2 * t + 1 < NBLK_SCAN) ? bsum[2 * t + 1] : 0;
    int s = c0 + c1;
    int v = s;
#pragma unroll
    for (int off = 1; off < 64; off <<= 1) {
        int u = __shfl_up(v, off, 64);
        if (t >= off) v += u;
    }
    int excl = v - s;
    if (2 * t     < NBLK_SCAN) boffset[2 * t]     = excl;
    if (2 * t + 1 < NBLK_SCAN) boffset[2 * t + 1] = excl + c0;
    if (t == 0) row_ptr[N_NODES] = N_EDGES;
}

__global__ __launch_bounds__(256) void scan_write_kernel(const int* __restrict__ counts,
                                                         const int* __restrict__ boffset,
                                                         int* __restrict__ row_ptr,
                                                         int* __restrict__ bcurs) {
    __shared__ int wsh[4];
    const int t = threadIdx.x, lane = t & 63, wv = t >> 6;
    int idx = blockIdx.x * 1024 + t * 4;
    int4 c = make_int4(0, 0, 0, 0);
    if (idx < N_NODES) c = *(const int4*)(counts + idx);
    int s = c.x + c.y + c.z + c.w;

    int v = s;
#pragma unroll
    for (int off = 1; off < 64; off <<= 1) {
        int u = __shfl_up(v, off, 64);
        if (lane >= off) v += u;
    }
    if (lane == 63) wsh[wv] = v;
    __syncthreads();
    int wave_excl = 0;
#pragma unroll
    for (int w = 0; w < 4; ++w) wave_excl += (w < wv) ? wsh[w] : 0;

    if (idx < N_NODES) {
        int p = boffset[blockIdx.x] + wave_excl + (v - s);
        int4 r;
        r.x = p;
        r.y = p + c.x;
        r.z = r.y + c.y;
        r.w = r.z + c.z;
        *(int4*)(row_ptr + idx) = r;
        if ((idx & 63) == 0) bcurs[idx >> BSHIFT] = p;  // bucket window base
    }
}

// ---------------------------------------------------------------------------
// Fill pass 1: edge -> its bucket window (frontier = NB L2-resident lines).
// Pack: bits 0..16 src, bits 17..22 dst&63; .y = val bits.
// ---------------------------------------------------------------------------
__global__ __launch_bounds__(256) void fill_bucket_kernel(const int* __restrict__ src,
                                                          const int* __restrict__ dst,
                                                          const float* __restrict__ vals,
                                                          int* __restrict__ bcurs,
                                                          uint2* __restrict__ etmp) {
    int e = blockIdx.x * 256 + threadIdx.x;
    if (e < N_EDGES) {
        int d = dst[e];
        int pos = atomicAdd(&bcurs[d >> BSHIFT], 1);
        etmp[pos] = make_uint2((unsigned)src[e] | ((unsigned)(d & 63) << 17),
                               __float_as_uint(vals[e]));
    }
}

// ---------------------------------------------------------------------------
// Fill pass 2: within-bucket counting sort to per-node order via 64 LDS
// cursors. Reads sequential, writes confined to the bucket's ~8 KB window.
// ---------------------------------------------------------------------------
__global__ __launch_bounds__(256) void fill_sort_kernel(const uint2* __restrict__ etmp,
                                                        const int* __restrict__ row_ptr,
                                                        uint2* __restrict__ ep) {
    __shared__ int cur[NPB];
    const int t = threadIdx.x;
    const int b = blockIdx.x;
    const int n0 = b * NPB;
    if (t < NPB) {
        int n = n0 + t;
        cur[t] = row_ptr[n < N_NODES ? n : N_NODES];
    }
    __syncthreads();
    const int jb = row_ptr[n0];
    const int nend = n0 + NPB;
    const int je = row_ptr[nend < N_NODES ? nend : N_NODES];
    for (int j = jb + t; j < je; j += 256) {
        uint2 p = etmp[j];
        int dl = (p.x >> 17) & 63;
        int pos = atomicAdd(&cur[dl], 1);
        ep[pos] = make_uint2(p.x & 0x1FFFFu, p.y);
    }
}

// ---------------------------------------------------------------------------
// Gather: one wave per node, bf16 h rows (256 B = 64 lanes x 1 uint).
// Deterministic ownership: each out row written exactly once.
// ---------------------------------------------------------------------------
__global__ __launch_bounds__(256) void gather_bf16_kernel(
        const unsigned int* __restrict__ hbits,  // [N_NODES][64]
        const int* __restrict__ row_ptr,
        const uint2* __restrict__ ep,
        float2* __restrict__ out2)
{
    const int lane = threadIdx.x & 63;
    const int node = blockIdx.x * 4 + (threadIdx.x >> 6);
    if (node >= N_NODES) return;

    const int jb = row_ptr[node];
    const int je = row_ptr[node + 1];

    float ax0 = 0.f, ay0 = 0.f, ax1 = 0.f, ay1 = 0.f;

    int j = jb;
    for (; j + 1 < je; j += 2) {
        uint2 e0 = ep[j], e1 = ep[j + 1];
        unsigned b0 = hbits[(size_t)e0.x * 64 + lane];
        unsigned b1 = hbits[(size_t)e1.x * 64 + lane];
        float v0 = __uint_as_float(e0.y), v1 = __uint_as_float(e1.y);
        ax0 += v0 * __uint_as_float(b0 << 16);
        ay0 += v0 * __uint_as_float(b0 & 0xffff0000u);
        ax1 += v1 * __uint_as_float(b1 << 16);
        ay1 += v1 * __uint_as_float(b1 & 0xffff0000u);
    }
    if (j < je) {
        uint2 e0 = ep[j];
        unsigned b0 = hbits[(size_t)e0.x * 64 + lane];
        float v0 = __uint_as_float(e0.y);
        ax0 += v0 * __uint_as_float(b0 << 16);
        ay0 += v0 * __uint_as_float(b0 & 0xffff0000u);
    }
    out2[(size_t)node * 64 + lane] = make_float2(ax0 + ax1, ay0 + ay1);
}

// ---------------------------------------------------------------------------
// Fallback scatter (atomic) on bf16 h, if workspace too small
// ---------------------------------------------------------------------------
__global__ __launch_bounds__(256) void scatter_kernel(
        const unsigned int* __restrict__ hbits, const float* __restrict__ vals,
        const int* __restrict__ src, const int* __restrict__ dst,
        float* __restrict__ out)
{
    const int lane = threadIdx.x & 63;
    int e = (blockIdx.x * 256 + threadIdx.x) >> 6;
    if (e >= N_EDGES) return;
    const int   s = src[e];
    const int   d = dst[e];
    const float v = vals[e];
    unsigned b = hbits[(size_t)s * 64 + lane];
    float* op = out + (size_t)d * DIM + lane * 2;
    atomicAdd(op + 0, v * __uint_as_float(b << 16));
    atomicAdd(op + 1, v * __uint_as_float(b & 0xffff0000u));
}

// ---------------------------------------------------------------------------
extern "C" void kernel_launch(void* const* d_in, const int* in_sizes, int n_in,
                              void* d_out, int out_size, void* d_ws, size_t ws_size,
                              hipStream_t stream) {
    const float* x    = (const float*)d_in[0];
    const float* W    = (const float*)d_in[1];
    const float* vals = (const float*)d_in[2];
    const int*   src  = (const int*)d_in[3];
    const int*   dst  = (const int*)d_in[4];
    float* out = (float*)d_out;

    char* ws = (char*)d_ws;
    unsigned* hbits = (unsigned*)(ws + OFF_H);
    int*   row_ptr  = (int*)  (ws + OFF_ROWPTR);
    int*   counts   = (int*)  (ws + OFF_COUNTS);
    int*   bsum     = (int*)  (ws + OFF_BSUM);
    int*   boffset  = bsum + 128;
    int*   bcurs    = (int*)  (ws + OFF_BCURS);
    uint2* etmp     = (uint2*)(ws + OFF_ETMP);
    uint2* ep       = (uint2*)(ws + OFF_EPACK);

    // GEMM: h = bf16(x @ W^T)
    gemm_tiled_kernel<<<(N_NODES + GR - 1) / GR, 256, 0, stream>>>(
        (const float4*)x, (const float4*)W, hbits);

    if (ws_size >= (size_t)WS_NEED) {
        zero_counts_kernel<<<(100032 / 4 + 255) / 256, 256, 0, stream>>>((int4*)counts);
        hist_kernel<<<(N_EDGES + 255) / 256, 256, 0, stream>>>(dst, counts);
        scan_bsum_kernel<<<NBLK_SCAN, 256, 0, stream>>>(counts, bsum);
        scan_boff_kernel<<<1, 64, 0, stream>>>(bsum, boffset, row_ptr);
        scan_write_kernel<<<NBLK_SCAN, 256, 0, stream>>>(counts, boffset, row_ptr, bcurs);
        fill_bucket_kernel<<<(N_EDGES + 255) / 256, 256, 0, stream>>>(src, dst, vals,
                                                                      bcurs, etmp);
        fill_sort_kernel<<<NB, 256, 0, stream>>>(etmp, row_ptr, ep);
        gather_bf16_kernel<<<(N_NODES + 3) / 4, 256, 0, stream>>>(
            hbits, row_ptr, ep, (float2*)out);
    } else {
        zero_out_kernel<<<(N_NODES * DIM / 4 + 255) / 256, 256, 0, stream>>>((float4*)out);
        scatter_kernel<<<(N_EDGES * 64 + 255) / 256, 256, 0, stream>>>(
            hbits, vals, src, dst, out);
    }
}

// Round 6
// 447.569 us; speedup vs baseline: 3.5264x; 1.2914x over previous
//
#include <hip/hip_runtime.h>

#define N_NODES 100000
#define N_EDGES 1600000
#define DIM 128
#define NPB 4                        // nodes per bucket
#define NB 25000                     // N_NODES / NPB (exact)
#define NCH 128                      // chunks
#define EPC 12500                    // edges per chunk (exact: 128*12500 = 1.6M)
#define NBLK_SCAN 25                 // ceil(25000/1024)

// ---------------- workspace layout (bytes, 128-aligned) --------------------
#define OFF_H       0                // bf16 [N_NODES][128]    25,600,000
#define OFF_BPTR    25600000         // int [NB+1]                100,096
#define OFF_BTOT    25700096         // int [NB]                  100,096
#define OFF_BSUM    25800192         // int[64]+int[64]             1,024
#define OFF_HIST    25801216         // int [NCH][NB]          12,800,000
#define OFF_EPACK   38601216         // uint2 [N_EDGES]        12,800,000
#define WS_NEED     51401216

static __device__ __forceinline__ unsigned short f2bf(float f) {
    union { float f; unsigned u; } a; a.f = f;
    unsigned r = a.u + 0x7fffu + ((a.u >> 16) & 1u);  // round-to-nearest-even
    return (unsigned short)(r >> 16);
}

// XCD-permuted chunk order: adjacent sub-windows in a bucket belong to chunks
// with equal (c & 7) -> same XCD under blockIdx%8 round-robin (perf heuristic
// only; correctness independent of the real mapping).
static __device__ __forceinline__ int sigma(int k) {
    return ((k & 15) << 3) | (k >> 4);
}

// ---------------------------------------------------------------------------
__global__ __launch_bounds__(256) void zero_out_kernel(float4* __restrict__ out) {
    int i = blockIdx.x * 256 + threadIdx.x;
    if (i < N_NODES * DIM / 4) out[i] = make_float4(0.f, 0.f, 0.f, 0.f);
}

__global__ __launch_bounds__(256) void zero_hist_kernel(int4* __restrict__ p) {
    int i = blockIdx.x * 256 + threadIdx.x;
    if (i < NCH * NB / 4) p[i] = make_int4(0, 0, 0, 0);
}

// ---------------------------------------------------------------------------
// GEMM h = x @ W^T (fp32 accumulate, bf16 output). Proven since R3.
// ---------------------------------------------------------------------------
#define GR 64
__global__ __launch_bounds__(256) void gemm_tiled_kernel(
        const float4* __restrict__ x4,        // [N_NODES][32]
        const float4* __restrict__ W4,        // [128][32]
        unsigned int* __restrict__ hbits)     // [N_NODES][64] (2 bf16 / uint)
{
    __shared__ float xs[GR][68];
    __shared__ float wsh[64][132];

    const int t  = threadIdx.x;
    const int tx = t & 15;
    const int ty = t >> 4;
    const int r0 = blockIdx.x * GR;

    float acc[4][8];
#pragma unroll
    for (int i = 0; i < 4; ++i)
#pragma unroll
        for (int j = 0; j < 8; ++j) acc[i][j] = 0.f;

    for (int kc = 0; kc < 2; ++kc) {
#pragma unroll
        for (int i = 0; i < 4; ++i) {
            int linear = t + 256 * i;
            int r  = linear >> 4;
            int k4 = linear & 15;
            float4 v = make_float4(0.f, 0.f, 0.f, 0.f);
            if (r0 + r < N_NODES) v = x4[(size_t)(r0 + r) * 32 + kc * 16 + k4];
            *(float4*)&xs[r][k4 * 4] = v;
        }
#pragma unroll
        for (int i = 0; i < 8; ++i) {
            int linear = t + 256 * i;
            int c  = linear >> 4;
            int k4 = linear & 15;
            float4 v = W4[(size_t)c * 32 + kc * 16 + k4];
            wsh[k4 * 4 + 0][c] = v.x;
            wsh[k4 * 4 + 1][c] = v.y;
            wsh[k4 * 4 + 2][c] = v.z;
            wsh[k4 * 4 + 3][c] = v.w;
        }
        __syncthreads();

#pragma unroll 4
        for (int kk = 0; kk < 64; ++kk) {
            float xf[4], wf[8];
#pragma unroll
            for (int i = 0; i < 4; ++i) xf[i] = xs[ty * 4 + i][kk];
            float4 wlo = *(const float4*)&wsh[kk][tx * 8];
            float4 whi = *(const float4*)&wsh[kk][tx * 8 + 4];
            wf[0] = wlo.x; wf[1] = wlo.y; wf[2] = wlo.z; wf[3] = wlo.w;
            wf[4] = whi.x; wf[5] = whi.y; wf[6] = whi.z; wf[7] = whi.w;
#pragma unroll
            for (int i = 0; i < 4; ++i)
#pragma unroll
                for (int j = 0; j < 8; ++j) acc[i][j] += xf[i] * wf[j];
        }
        __syncthreads();
    }

#pragma unroll
    for (int i = 0; i < 4; ++i) {
        int r = r0 + ty * 4 + i;
        if (r < N_NODES) {
            uint4 u;
            u.x = (unsigned)f2bf(acc[i][0]) | ((unsigned)f2bf(acc[i][1]) << 16);
            u.y = (unsigned)f2bf(acc[i][2]) | ((unsigned)f2bf(acc[i][3]) << 16);
            u.z = (unsigned)f2bf(acc[i][4]) | ((unsigned)f2bf(acc[i][5]) << 16);
            u.w = (unsigned)f2bf(acc[i][6]) | ((unsigned)f2bf(acc[i][7]) << 16);
            *(uint4*)&hbits[(size_t)r * 64 + tx * 4] = u;
        }
    }
}

// ---------------------------------------------------------------------------
// Chunked counting sort, pass 1: per-chunk bucket histogram.
// hist[c][*] is block-private (atomics local to one XCD's L2, uncontended).
// ---------------------------------------------------------------------------
__global__ __launch_bounds__(256) void chunk_hist_kernel(const int* __restrict__ dst,
                                                         int* __restrict__ hist) {
    const int c = blockIdx.x;
    const int e0 = c * EPC;
    int* hrow = hist + (size_t)c * NB;
    for (int i = threadIdx.x; i < EPC; i += 256)
        atomicAdd(&hrow[dst[e0 + i] >> 2], 1);
}

// Per-bucket totals: lane = bucket, loop chunks (coalesced 256 B loads).
__global__ __launch_bounds__(64) void btot_kernel(const int* __restrict__ hist,
                                                  int* __restrict__ btot) {
    int b = blockIdx.x * 64 + threadIdx.x;
    if (b >= NB) return;
    int s = 0;
#pragma unroll 8
    for (int c = 0; c < NCH; ++c) s += hist[(size_t)c * NB + b];
    btot[b] = s;
}

// ---------------------------------------------------------------------------
// 3-kernel exclusive scan of btot[NB] -> bptr
// ---------------------------------------------------------------------------
__global__ __launch_bounds__(256) void scan_bsum_kernel(const int* __restrict__ btot,
                                                        int* __restrict__ bsum) {
    __shared__ int wsh[4];
    const int t = threadIdx.x, lane = t & 63, wv = t >> 6;
    int idx = blockIdx.x * 1024 + t * 4;
    int s = 0;
    if (idx < NB) {   // NB % 4 == 0 -> whole int4 in-bounds
        int4 c = *(const int4*)(btot + idx);
        s = c.x + c.y + c.z + c.w;
    }
#pragma unroll
    for (int off = 32; off > 0; off >>= 1) s += __shfl_down(s, off, 64);
    if (lane == 0) wsh[wv] = s;
    __syncthreads();
    if (t == 0) bsum[blockIdx.x] = wsh[0] + wsh[1] + wsh[2] + wsh[3];
}

__global__ __launch_bounds__(64) void scan_boff_kernel(const int* __restrict__ bsum,
                                                       int* __restrict__ boffset,
                                                       int* __restrict__ bptr) {
    const int t = threadIdx.x;
    int c0 = (2 * t     < NBLK_SCAN) ? bsum[2 * t]     : 0;
    int c1 = (2 * t + 1 < NBLK_SCAN) ? bsum[2 * t + 1] : 0;
    int s = c0 + c1;
    int v = s;
#pragma unroll
    for (int off = 1; off < 64; off <<= 1) {
        int u = __shfl_up(v, off, 64);
        if (t >= off) v += u;
    }
    int excl = v - s;
    if (2 * t     < NBLK_SCAN) boffset[2 * t]     = excl;
    if (2 * t + 1 < NBLK_SCAN) boffset[2 * t + 1] = excl + c0;
    if (t == 0) bptr[NB] = N_EDGES;
}

__global__ __launch_bounds__(256) void scan_write_kernel(const int* __restrict__ btot,
                                                         const int* __restrict__ boffset,
                                                         int* __restrict__ bptr) {
    __shared__ int wsh[4];
    const int t = threadIdx.x, lane = t & 63, wv = t >> 6;
    int idx = blockIdx.x * 1024 + t * 4;
    int4 c = make_int4(0, 0, 0, 0);
    if (idx < NB) c = *(const int4*)(btot + idx);
    int s = c.x + c.y + c.z + c.w;

    int v = s;
#pragma unroll
    for (int off = 1; off < 64; off <<= 1) {
        int u = __shfl_up(v, off, 64);
        if (lane >= off) v += u;
    }
    if (lane == 63) wsh[wv] = v;
    __syncthreads();
    int wave_excl = 0;
#pragma unroll
    for (int w = 0; w < 4; ++w) wave_excl += (w < wv) ? wsh[w] : 0;

    if (idx < NB) {
        int p = boffset[blockIdx.x] + wave_excl + (v - s);
        int4 r;
        r.x = p;
        r.y = p + c.x;
        r.z = r.y + c.y;
        r.w = r.z + c.z;
        *(int4*)(bptr + idx) = r;
    }
}

// ---------------------------------------------------------------------------
// Segmented scan: hist[c][b] (counts) -> absolute start offsets, in-place,
// iterating chunks in XCD-permuted order. Lane = bucket; loads batched 4-wide
// to break the serial load-latency chain.
// ---------------------------------------------------------------------------
__global__ __launch_bounds__(64) void seg_scan_kernel(int* __restrict__ hist,
                                                      const int* __restrict__ bptr) {
    int b = blockIdx.x * 64 + threadIdx.x;
    if (b >= NB) return;
    int run = bptr[b];
    for (int k = 0; k < NCH; k += 4) {
        size_t i0 = (size_t)sigma(k)     * NB + b;
        size_t i1 = (size_t)sigma(k + 1) * NB + b;
        size_t i2 = (size_t)sigma(k + 2) * NB + b;
        size_t i3 = (size_t)sigma(k + 3) * NB + b;
        int v0 = hist[i0], v1 = hist[i1], v2 = hist[i2], v3 = hist[i3];
        hist[i0] = run; run += v0;
        hist[i1] = run; run += v1;
        hist[i2] = run; run += v2;
        hist[i3] = run; run += v3;
    }
}

// ---------------------------------------------------------------------------
// Chunked counting sort, pass 2: place edges. Cursors are block-private rows
// of hist (now offsets); sub-windows written by exactly one block -> no
// cross-XCD line sharing (modulo the c%8 heuristic).
// Pack: bits 0..16 src, bits 17..18 dst&3; .y = val bits.
// ---------------------------------------------------------------------------
__global__ __launch_bounds__(256) void cplace_kernel(const int* __restrict__ src,
                                                     const int* __restrict__ dst,
                                                     const float* __restrict__ vals,
                                                     int* __restrict__ hist,
                                                     uint2* __restrict__ ep) {
    const int c = blockIdx.x;
    const int e0 = c * EPC;
    int* cur = hist + (size_t)c * NB;
    for (int i = threadIdx.x; i < EPC; i += 256) {
        int e = e0 + i;
        int d = dst[e];
        int pos = atomicAdd(&cur[d >> 2], 1);
        ep[pos] = make_uint2((unsigned)src[e] | ((unsigned)(d & 3) << 17),
                             __float_as_uint(vals[e]));
    }
}

// ---------------------------------------------------------------------------
// Gather: block = 1 bucket (4 nodes), wave w = node 4b+w. Lanes cooperatively
// load up to 64 edge packs, ballot the dst-match, iterate set bits via shfl;
// per matching edge the 64 lanes load the 256 B bf16 h row. Each out row
// written exactly once (handles poison).
// ---------------------------------------------------------------------------
__global__ __launch_bounds__(256) void gather_kernel(
        const unsigned int* __restrict__ hbits,  // [N_NODES][64]
        const int* __restrict__ bptr,
        const uint2* __restrict__ ep,
        float2* __restrict__ out2)
{
    const int lane = threadIdx.x & 63;
    const int w    = threadIdx.x >> 6;      // 0..3
    const int b    = blockIdx.x;

    const int jb = bptr[b], je = bptr[b + 1];

    float ax = 0.f, ay = 0.f;

    for (int base = jb; base < je; base += 64) {
        int navail = je - base;
        uint2 p = make_uint2(0u, 0u);
        if (lane < navail) p = ep[base + lane];
        bool match = (lane < navail) && (((p.x >> 17) & 3u) == (unsigned)w);
        unsigned long long m = __ballot(match);
        while (m) {
            int s = __ffsll(m) - 1;
            m &= m - 1;
            unsigned px = __shfl(p.x, s, 64);
            unsigned pv = __shfl(p.y, s, 64);
            unsigned hb = hbits[(size_t)(px & 0x1FFFFu) * 64 + lane];
            float v = __uint_as_float(pv);
            ax += v * __uint_as_float(hb << 16);
            ay += v * __uint_as_float(hb & 0xffff0000u);
        }
    }
    out2[(size_t)(b * 4 + w) * 64 + lane] = make_float2(ax, ay);
}

// ---------------------------------------------------------------------------
// Fallback scatter (atomic) on bf16 h, if workspace too small
// ---------------------------------------------------------------------------
__global__ __launch_bounds__(256) void scatter_kernel(
        const unsigned int* __restrict__ hbits, const float* __restrict__ vals,
        const int* __restrict__ src, const int* __restrict__ dst,
        float* __restrict__ out)
{
    const int lane = threadIdx.x & 63;
    int e = (blockIdx.x * 256 + threadIdx.x) >> 6;
    if (e >= N_EDGES) return;
    const int   s = src[e];
    const int   d = dst[e];
    const float v = vals[e];
    unsigned b = hbits[(size_t)s * 64 + lane];
    float* op = out + (size_t)d * DIM + lane * 2;
    atomicAdd(op + 0, v * __uint_as_float(b << 16));
    atomicAdd(op + 1, v * __uint_as_float(b & 0xffff0000u));
}

// ---------------------------------------------------------------------------
extern "C" void kernel_launch(void* const* d_in, const int* in_sizes, int n_in,
                              void* d_out, int out_size, void* d_ws, size_t ws_size,
                              hipStream_t stream) {
    const float* x    = (const float*)d_in[0];
    const float* W    = (const float*)d_in[1];
    const float* vals = (const float*)d_in[2];
    const int*   src  = (const int*)d_in[3];
    const int*   dst  = (const int*)d_in[4];
    float* out = (float*)d_out;

    char* ws = (char*)d_ws;
    unsigned* hbits = (unsigned*)(ws + OFF_H);
    int*   bptr     = (int*)  (ws + OFF_BPTR);
    int*   btot     = (int*)  (ws + OFF_BTOT);
    int*   bsum     = (int*)  (ws + OFF_BSUM);
    int*   boffset  = bsum + 128;
    int*   hist     = (int*)  (ws + OFF_HIST);
    uint2* ep       = (uint2*)(ws + OFF_EPACK);

    // GEMM: h = bf16(x @ W^T)
    gemm_tiled_kernel<<<(N_NODES + GR - 1) / GR, 256, 0, stream>>>(
        (const float4*)x, (const float4*)W, hbits);

    if (ws_size >= (size_t)WS_NEED) {
        zero_hist_kernel<<<(NCH * NB / 4 + 255) / 256, 256, 0, stream>>>((int4*)hist);
        chunk_hist_kernel<<<NCH, 256, 0, stream>>>(dst, hist);
        btot_kernel<<<(NB + 63) / 64, 64, 0, stream>>>(hist, btot);
        scan_bsum_kernel<<<NBLK_SCAN, 256, 0, stream>>>(btot, bsum);
        scan_boff_kernel<<<1, 64, 0, stream>>>(bsum, boffset, bptr);
        scan_write_kernel<<<NBLK_SCAN, 256, 0, stream>>>(btot, boffset, bptr);
        seg_scan_kernel<<<(NB + 63) / 64, 64, 0, stream>>>(hist, bptr);
        cplace_kernel<<<NCH, 256, 0, stream>>>(src, dst, vals, hist, ep);
        gather_kernel<<<NB, 256, 0, stream>>>(hbits, bptr, ep, (float2*)out);
    } else {
        zero_out_kernel<<<(N_NODES * DIM / 4 + 255) / 256, 256, 0, stream>>>((float4*)out);
        scatter_kernel<<<(N_EDGES * 64 + 255) / 256, 256, 0, stream>>>(
            hbits, vals, src, dst, out);
    }
}